// Round 11
// baseline (322.947 us; speedup 1.0000x reference)
//
#include <hip/hip_runtime.h>

#define B_ 256
#define S_ 512
#define V_ 50000
#define D_ 256
#define L_ 128
#define PGRID 512

typedef __attribute__((ext_vector_type(8))) short short8;
typedef __attribute__((ext_vector_type(4))) float floatx4;

// ws layout (float units):
// [0..16)   ctrl: [1]=kl_acc(f32), [2]=vc(i32), [3]=done(i32)
// [16..272)   sqp (256 f32)
// [272..528)  lens (256 i32)
// [528..+65536)   Q (f32)
// [66064..+32768) Wt (bf16 Wout^T)
// [98832..+524288) enc_part (256 b x 8 o x 256 d, f32)
// [623120..+6400000) embb (bf16)
// [7023120..+6400000) P (bf16)
#define OFF_SQP  16
#define OFF_LENS 272
#define OFF_Q    528
#define OFF_WT   (OFF_Q + B_ * D_)
#define OFF_EP   (OFF_WT + 32768)
#define OFF_EB   (OFF_EP + B_ * 8 * D_)
#define OFF_P    (OFF_EB + (V_ * D_ / 2))

__device__ __forceinline__ unsigned short f2bf(float x) {
    unsigned u = __float_as_uint(x);
    u += 0x7FFFu + ((u >> 16) & 1u);
    return (unsigned short)(u >> 16);
}
__device__ __forceinline__ float bf2f(unsigned short u) {
    return __uint_as_float(((unsigned)u) << 16);
}

// ---- prep: embb = bf16(emb); Wt = bf16(Wout^T); zero ctrl + sqp ----
__global__ __launch_bounds__(256) void prep_kernel(const float* __restrict__ emb,
                                                   const float* __restrict__ Wout,
                                                   unsigned short* __restrict__ embb,
                                                   unsigned short* __restrict__ Wt,
                                                   float* __restrict__ ws) {
    __shared__ float sT[64][65];
    const int tid = threadIdx.x;
    if (blockIdx.x == 0) {
        if (tid < 16) ((int*)ws)[tid] = 0;
        ws[OFF_SQP + tid] = 0.f;
    }
    if (blockIdx.x < 16) {
        const int bx = blockIdx.x;
        const int k0 = (bx & 3) * 64, n0 = (bx >> 2) * 64;
        const int c = tid & 63, rg = tid >> 6;
#pragma unroll
        for (int i = 0; i < 16; ++i) {
            int r = rg * 16 + i;
            sT[c][r] = Wout[(k0 + r) * D_ + n0 + c];
        }
        __syncthreads();
#pragma unroll
        for (int i = 0; i < 16; ++i) {
            int r = rg * 16 + i;
            Wt[(size_t)(n0 + r) * D_ + k0 + c] = f2bf(sT[r][c]);
        }
    }
    const int N4 = V_ * D_ / 4;
    for (int i = blockIdx.x * 256 + tid; i < N4; i += gridDim.x * 256) {
        float4 v = ((const float4*)emb)[i];
        ushort4 h;
        h.x = f2bf(v.x); h.y = f2bf(v.y); h.z = f2bf(v.z); h.w = f2bf(v.w);
        ((ushort4*)embb)[i] = h;
    }
}

// ---- P = embb @ Wout: B-in-registers persistent GEMM, A prefetch ----
__global__ __launch_bounds__(256, 2) void pgemm_kernel(
    const unsigned short* __restrict__ embb, const unsigned short* __restrict__ Wt,
    unsigned short* __restrict__ P) {
    const int tid = threadIdx.x;
    const int wv = tid >> 6, lane = tid & 63;
    const int lo = lane & 15, hi = lane >> 4;
    const int NCH = V_ / 16;  // 3125

    short8 bfr[4][8];
    const unsigned short* wbase = Wt + (size_t)(wv * 64 + lo) * D_ + hi * 8;
#pragma unroll
    for (int nt = 0; nt < 4; ++nt)
#pragma unroll
        for (int kk = 0; kk < 8; ++kk)
            bfr[nt][kk] = *(const short8*)(wbase + nt * 16 * D_ + kk * 32);

    int ch = blockIdx.x;
    const unsigned short* abase = embb + (size_t)(ch * 16 + lo) * D_ + hi * 8;
    short8 acur[8];
#pragma unroll
    for (int kk = 0; kk < 8; ++kk) acur[kk] = *(const short8*)(abase + kk * 32);

    for (; ch < NCH; ch += PGRID) {
        const int chn = (ch + PGRID < NCH) ? (ch + PGRID) : ch;
        const unsigned short* anext = embb + (size_t)(chn * 16 + lo) * D_ + hi * 8;
        short8 anxt[8];
#pragma unroll
        for (int kk = 0; kk < 8; ++kk) anxt[kk] = *(const short8*)(anext + kk * 32);

        floatx4 acc[4];
#pragma unroll
        for (int nt = 0; nt < 4; ++nt) acc[nt] = (floatx4){0.f, 0.f, 0.f, 0.f};
#pragma unroll
        for (int kk = 0; kk < 8; ++kk)
#pragma unroll
            for (int nt = 0; nt < 4; ++nt)
                acc[nt] = __builtin_amdgcn_mfma_f32_16x16x32_bf16(
                    acur[kk], bfr[nt][kk], acc[nt], 0, 0, 0);

#pragma unroll
        for (int r = 0; r < 4; ++r) {
            unsigned short* prow = P + (size_t)(ch * 16 + hi * 4 + r) * D_ + wv * 64 + lo;
#pragma unroll
            for (int nt = 0; nt < 4; ++nt) prow[nt * 16] = f2bf(acc[nt][r]);
        }
#pragma unroll
        for (int kk = 0; kk < 8; ++kk) acur[kk] = anxt[kk];
    }
}

// ---- gather: 8 blocks per b (stride-8 interleave), partials to enc_part ----
__global__ __launch_bounds__(256) void gather_kernel(
    const int* __restrict__ vocab, const int* __restrict__ order,
    const int* __restrict__ mask, const unsigned short* __restrict__ embb,
    float* __restrict__ enc_part) {
    const int b = blockIdx.x >> 3, o = blockIdx.x & 7;
    const int tid = threadIdx.x;
    const int jg = tid >> 6, lane = tid & 63;
    const ushort4* eb4 = (const ushort4*)embb;
    float4 a = {0.f, 0.f, 0.f, 0.f};
    for (int j = o + 8 * jg; j < S_; j += 32) {     // j wave-uniform
        if (!mask[b * S_ + j]) break;               // prefix mask -> uniform break
        int id1 = vocab[b * S_ + j];
        int id2;
        if (j == 0) {
            id2 = 1;  // BOS
        } else {
            int oi = order[(size_t)(b * S_ + j) * 6];
            if (oi == -1) oi = 1;
            id2 = mask[b * S_ + oi] ? vocab[b * S_ + oi] : 0;  // parent from vt
        }
        ushort4 x = eb4[(size_t)id1 * 64 + lane];
        ushort4 y = eb4[(size_t)id2 * 64 + lane];
        a.x += bf2f(x.x) + bf2f(y.x);
        a.y += bf2f(x.y) + bf2f(y.y);
        a.z += bf2f(x.z) + bf2f(y.z);
        a.w += bf2f(x.w) + bf2f(y.w);
    }
    __shared__ float4 sp[3][64];
    if (jg) sp[jg - 1][lane] = a;
    __syncthreads();
    if (jg == 0) {
#pragma unroll
        for (int g = 0; g < 3; ++g) {
            float4 p = sp[g][lane];
            a.x += p.x; a.y += p.y; a.z += p.z; a.w += p.w;
        }
        *(float4*)(enc_part + (size_t)blockIdx.x * D_ + 4 * lane) = a;
    }
}

// ---- latent: sum partials, cnt, latent chain, Q/lens/kl/vc ----
__global__ __launch_bounds__(256) void latent_kernel(
    const int* __restrict__ mask, const float* __restrict__ enc_part,
    const float* __restrict__ eps,
    const float* __restrict__ Wm, const float* __restrict__ bm,
    const float* __restrict__ Wv, const float* __restrict__ bv,
    const float* __restrict__ Wlin, const float* __restrict__ blin,
    const float* __restrict__ Wout, const float* __restrict__ bout,
    int* __restrict__ lens, float* __restrict__ Q,
    float* __restrict__ kl_acc, int* __restrict__ vc_acc) {
    __shared__ float s_enc[D_];
    __shared__ float s_mean[L_], s_lv[L_], s_z[L_], s_mem[D_];
    __shared__ float s_red[256];
    __shared__ int s_cnt;
    const int b = blockIdx.x;
    const int tid = threadIdx.x;
    if (tid == 0) s_cnt = 0;
    __syncthreads();
    {
        int m0 = mask[b * S_ + tid] != 0;
        int m1 = mask[b * S_ + 256 + tid] != 0;
        unsigned long long b0 = __ballot(m0), b1 = __ballot(m1);
        if ((tid & 63) == 0) atomicAdd(&s_cnt, __popcll(b0) + __popcll(b1));
    }
    __syncthreads();
    const int cnt = s_cnt;
    float e = 0.f;
#pragma unroll
    for (int o = 0; o < 8; ++o) e += enc_part[((size_t)(b * 8 + o)) * D_ + tid];
    s_enc[tid] = e / fmaxf((float)cnt, 1.f);
    __syncthreads();
    {
        const int l = tid & (L_ - 1);
        const float* W = (tid < L_) ? Wm : Wv;
        const float* bb = (tid < L_) ? bm : bv;
        float dot = bb[l];
        for (int d = 0; d < D_; ++d) dot = fmaf(s_enc[d], W[d * L_ + l], dot);
        if (tid < L_) s_mean[l] = dot; else s_lv[l] = dot;
    }
    __syncthreads();
    float klp = 0.f;
    if (tid < L_) {
        float mn = s_mean[tid], lv = s_lv[tid];
        s_z[tid] = mn + eps[b * L_ + tid] * expf(0.5f * lv);
        klp = 1.f + lv - mn * mn - expf(lv);
    }
    s_red[tid] = klp;
    __syncthreads();
    for (int s = 128; s > 0; s >>= 1) {
        if (tid < s) s_red[tid] += s_red[tid + s];
        __syncthreads();
    }
    if (tid == 0) {
        atomicAdd(kl_acc, s_red[0]);
        atomicAdd(vc_acc, cnt + 1);
        lens[b] = cnt;
    }
    float mem = blin[tid];
    for (int l2 = 0; l2 < L_; ++l2) mem = fmaf(s_z[l2], Wlin[l2 * D_ + tid], mem);
    s_mem[tid] = mem;
    __syncthreads();
    float qv = bout[tid];
    for (int k = 0; k < D_; ++k) qv = fmaf(s_mem[k], Wout[k * D_ + tid], qv);
    Q[b * D_ + tid] = qv;
}

// ---- scan: high-parallelism + fused last-block finalize ----
#define NBLK (17 * B_)
__global__ __launch_bounds__(256) void scan_kernel(
    const int* __restrict__ vocab, const unsigned short* __restrict__ embb,
    const unsigned short* __restrict__ P, const float* __restrict__ Q,
    const int* __restrict__ lens, float* __restrict__ ws,
    float* __restrict__ out) {
    __shared__ float s_red[256];
    __shared__ int s_prev;
    const int tid = threadIdx.x;
    const int wv = tid >> 6, lane = tid & 63;
    const int b = blockIdx.y, chunk = blockIdx.x;
    const int len = lens[b];
    const int j0 = chunk * 32 + wv * 8;
    float* kl_acc = ws + 1;
    int* vc_acc = (int*)ws + 2;
    int* done = (int*)ws + 3;
    float* sqp = ws + OFF_SQP;

    if (j0 <= len) {
        const int c = lane * 4;
        const float4 q4 = *(const float4*)(Q + (size_t)b * D_ + c);
        int inp[8], tgt[8];
        float wgt[8];
#pragma unroll
        for (int jj = 0; jj < 8; ++jj) {
            const int j = j0 + jj;
            const bool v = (j <= len);
            const int jc = v ? j : 0;
            inp[jj] = (jc == 0) ? 1 : vocab[b * S_ + jc - 1];
            tgt[jj] = v ? ((j < len) ? vocab[b * S_ + j] : ((len < S_) ? 2 : 1)) : 1;
            wgt[jj] = v ? 1.f : 0.f;
        }
        ushort4 pv[8], tv[8];
#pragma unroll
        for (int jj = 0; jj < 8; ++jj) {
            pv[jj] = *(const ushort4*)(P + (size_t)inp[jj] * D_ + c);
            tv[jj] = *(const ushort4*)(embb + (size_t)tgt[jj] * D_ + c);
        }
        float acc = 0.f;
#pragma unroll
        for (int jj = 0; jj < 8; ++jj) {
            float d0 = bf2f(pv[jj].x) + q4.x - bf2f(tv[jj].x);
            float d1 = bf2f(pv[jj].y) + q4.y - bf2f(tv[jj].y);
            float d2 = bf2f(pv[jj].z) + q4.z - bf2f(tv[jj].z);
            float d3 = bf2f(pv[jj].w) + q4.w - bf2f(tv[jj].w);
            float s = fmaf(d0, d0, fmaf(d1, d1, fmaf(d2, d2, d3 * d3)));
            acc = fmaf(wgt[jj], s, acc);
        }
#pragma unroll
        for (int off = 32; off; off >>= 1) acc += __shfl_down(acc, off, 64);
        if (lane == 0) atomicAdd(&sqp[(b * 4 + wv + chunk) & 255], acc);
    }
    __syncthreads();  // drain all waves' atomics (vmcnt(0) before barrier)
    if (tid == 0) {
        __threadfence();
        s_prev = atomicAdd(done, 1);
    }
    __syncthreads();
    if (s_prev == NBLK - 1) {
        float v = atomicAdd(&sqp[tid], 0.f);  // device-coherent read
        s_red[tid] = v;
        __syncthreads();
        for (int s = 128; s > 0; s >>= 1) {
            if (tid < s) s_red[tid] += s_red[tid + s];
            __syncthreads();
        }
        if (tid == 0) {
            float kl = atomicAdd(kl_acc, 0.f);
            int vc = atomicAdd(vc_acc, 0);
            long long denom = (long long)vc * D_;
            if (denom < 1) denom = 1;
            out[0] = s_red[0] / (float)denom;
            out[1] = -0.5f * kl / (float)B_;
        }
    }
}

extern "C" void kernel_launch(void* const* d_in, const int* in_sizes, int n_in,
                              void* d_out, int out_size, void* d_ws, size_t ws_size,
                              hipStream_t stream) {
    const int* vocab = (const int*)d_in[0];
    const int* order = (const int*)d_in[1];
    const int* mask  = (const int*)d_in[2];
    const float* eps  = (const float*)d_in[3];
    const float* emb  = (const float*)d_in[4];
    const float* Wm   = (const float*)d_in[5];
    const float* bm   = (const float*)d_in[6];
    const float* Wv   = (const float*)d_in[7];
    const float* bv   = (const float*)d_in[8];
    const float* Wlin = (const float*)d_in[9];
    const float* blin = (const float*)d_in[10];
    const float* Wout = (const float*)d_in[11];
    const float* bout = (const float*)d_in[12];

    float* ws = (float*)d_ws;
    int* lens = (int*)(ws + OFF_LENS);
    float* Q = ws + OFF_Q;
    unsigned short* Wt = (unsigned short*)(ws + OFF_WT);
    float* enc_part = ws + OFF_EP;
    unsigned short* embb = (unsigned short*)(ws + OFF_EB);
    unsigned short* P = (unsigned short*)(ws + OFF_P);

    prep_kernel<<<2048, 256, 0, stream>>>(emb, Wout, embb, Wt, ws);
    pgemm_kernel<<<PGRID, 256, 0, stream>>>(embb, Wt, P);
    gather_kernel<<<B_ * 8, 256, 0, stream>>>(vocab, order, mask, embb, enc_part);
    latent_kernel<<<B_, 256, 0, stream>>>(mask, enc_part, eps, Wm, bm, Wv, bv,
                                          Wlin, blin, Wout, bout, lens, Q,
                                          ws + 1, (int*)ws + 2);
    scan_kernel<<<dim3(17, B_), 256, 0, stream>>>(vocab, embb, P, Q, lens, ws,
                                                  (float*)d_out);
}

// Round 12
// 206.033 us; speedup vs baseline: 1.5675x; 1.5675x over previous
//
#include <hip/hip_runtime.h>

#define B_ 256
#define S_ 512
#define V_ 50000
#define D_ 256
#define L_ 128
#define PGRID 512

typedef __attribute__((ext_vector_type(8))) short short8;
typedef __attribute__((ext_vector_type(4))) float floatx4;

// ws layout (float units):
// [0..16)   ctrl: [1]=kl_acc(f32), [2]=vc(i32), [3]=done(i32)
// [16..272)   sqp (256 f32)
// [272..528)  lens (256 i32)
// [528..+65536)   Q (f32)
// [66064..+32768) Wt (bf16 Wout^T)
// [98832..+524288) enc_part (256 b x 8 o x 256 d, f32)
// [623120..+6400000) embb (bf16)
// [7023120..+6400000) P (bf16)
#define OFF_SQP  16
#define OFF_LENS 272
#define OFF_Q    528
#define OFF_WT   (OFF_Q + B_ * D_)
#define OFF_EP   (OFF_WT + 32768)
#define OFF_EB   (OFF_EP + B_ * 8 * D_)
#define OFF_P    (OFF_EB + (V_ * D_ / 2))

__device__ __forceinline__ unsigned short f2bf(float x) {
    unsigned u = __float_as_uint(x);
    u += 0x7FFFu + ((u >> 16) & 1u);
    return (unsigned short)(u >> 16);
}
__device__ __forceinline__ float bf2f(unsigned short u) {
    return __uint_as_float(((unsigned)u) << 16);
}

// ---- prep: embb = bf16(emb); Wt = bf16(Wout^T); zero ctrl + sqp ----
__global__ __launch_bounds__(256) void prep_kernel(const float* __restrict__ emb,
                                                   const float* __restrict__ Wout,
                                                   unsigned short* __restrict__ embb,
                                                   unsigned short* __restrict__ Wt,
                                                   float* __restrict__ ws) {
    __shared__ float sT[64][65];
    const int tid = threadIdx.x;
    if (blockIdx.x == 0) {
        if (tid < 16) ((int*)ws)[tid] = 0;
        ws[OFF_SQP + tid] = 0.f;
    }
    if (blockIdx.x < 16) {
        const int bx = blockIdx.x;
        const int k0 = (bx & 3) * 64, n0 = (bx >> 2) * 64;
        const int c = tid & 63, rg = tid >> 6;
#pragma unroll
        for (int i = 0; i < 16; ++i) {
            int r = rg * 16 + i;
            sT[c][r] = Wout[(k0 + r) * D_ + n0 + c];
        }
        __syncthreads();
#pragma unroll
        for (int i = 0; i < 16; ++i) {
            int r = rg * 16 + i;
            Wt[(size_t)(n0 + r) * D_ + k0 + c] = f2bf(sT[r][c]);
        }
    }
    const int N4 = V_ * D_ / 4;
    for (int i = blockIdx.x * 256 + tid; i < N4; i += gridDim.x * 256) {
        float4 v = ((const float4*)emb)[i];
        ushort4 h;
        h.x = f2bf(v.x); h.y = f2bf(v.y); h.z = f2bf(v.z); h.w = f2bf(v.w);
        ((ushort4*)embb)[i] = h;
    }
}

// ---- P = embb @ Wout: B-in-registers persistent GEMM, A prefetch ----
__global__ __launch_bounds__(256, 2) void pgemm_kernel(
    const unsigned short* __restrict__ embb, const unsigned short* __restrict__ Wt,
    unsigned short* __restrict__ P) {
    const int tid = threadIdx.x;
    const int wv = tid >> 6, lane = tid & 63;
    const int lo = lane & 15, hi = lane >> 4;
    const int NCH = V_ / 16;  // 3125

    short8 bfr[4][8];
    const unsigned short* wbase = Wt + (size_t)(wv * 64 + lo) * D_ + hi * 8;
#pragma unroll
    for (int nt = 0; nt < 4; ++nt)
#pragma unroll
        for (int kk = 0; kk < 8; ++kk)
            bfr[nt][kk] = *(const short8*)(wbase + nt * 16 * D_ + kk * 32);

    int ch = blockIdx.x;
    const unsigned short* abase = embb + (size_t)(ch * 16 + lo) * D_ + hi * 8;
    short8 acur[8];
#pragma unroll
    for (int kk = 0; kk < 8; ++kk) acur[kk] = *(const short8*)(abase + kk * 32);

    for (; ch < NCH; ch += PGRID) {
        const int chn = (ch + PGRID < NCH) ? (ch + PGRID) : ch;
        const unsigned short* anext = embb + (size_t)(chn * 16 + lo) * D_ + hi * 8;
        short8 anxt[8];
#pragma unroll
        for (int kk = 0; kk < 8; ++kk) anxt[kk] = *(const short8*)(anext + kk * 32);

        floatx4 acc[4];
#pragma unroll
        for (int nt = 0; nt < 4; ++nt) acc[nt] = (floatx4){0.f, 0.f, 0.f, 0.f};
#pragma unroll
        for (int kk = 0; kk < 8; ++kk)
#pragma unroll
            for (int nt = 0; nt < 4; ++nt)
                acc[nt] = __builtin_amdgcn_mfma_f32_16x16x32_bf16(
                    acur[kk], bfr[nt][kk], acc[nt], 0, 0, 0);

#pragma unroll
        for (int r = 0; r < 4; ++r) {
            unsigned short* prow = P + (size_t)(ch * 16 + hi * 4 + r) * D_ + wv * 64 + lo;
#pragma unroll
            for (int nt = 0; nt < 4; ++nt) prow[nt * 16] = f2bf(acc[nt][r]);
        }
#pragma unroll
        for (int kk = 0; kk < 8; ++kk) acur[kk] = anxt[kk];
    }
}

// ---- gather: 8 blocks per b (stride-8 interleave), partials to enc_part ----
__global__ __launch_bounds__(256) void gather_kernel(
    const int* __restrict__ vocab, const int* __restrict__ order,
    const int* __restrict__ mask, const unsigned short* __restrict__ embb,
    float* __restrict__ enc_part) {
    const int b = blockIdx.x >> 3, o = blockIdx.x & 7;
    const int tid = threadIdx.x;
    const int jg = tid >> 6, lane = tid & 63;
    const ushort4* eb4 = (const ushort4*)embb;
    float4 a = {0.f, 0.f, 0.f, 0.f};
    for (int j = o + 8 * jg; j < S_; j += 32) {     // j wave-uniform
        if (!mask[b * S_ + j]) break;               // prefix mask -> uniform break
        int id1 = vocab[b * S_ + j];
        int id2;
        if (j == 0) {
            id2 = 1;  // BOS
        } else {
            int oi = order[(size_t)(b * S_ + j) * 6];
            if (oi == -1) oi = 1;
            id2 = mask[b * S_ + oi] ? vocab[b * S_ + oi] : 0;  // parent from vt
        }
        ushort4 x = eb4[(size_t)id1 * 64 + lane];
        ushort4 y = eb4[(size_t)id2 * 64 + lane];
        a.x += bf2f(x.x) + bf2f(y.x);
        a.y += bf2f(x.y) + bf2f(y.y);
        a.z += bf2f(x.z) + bf2f(y.z);
        a.w += bf2f(x.w) + bf2f(y.w);
    }
    __shared__ float4 sp[3][64];
    if (jg) sp[jg - 1][lane] = a;
    __syncthreads();
    if (jg == 0) {
#pragma unroll
        for (int g = 0; g < 3; ++g) {
            float4 p = sp[g][lane];
            a.x += p.x; a.y += p.y; a.z += p.z; a.w += p.w;
        }
        *(float4*)(enc_part + (size_t)blockIdx.x * D_ + 4 * lane) = a;
    }
}

// ---- latent: sum partials, cnt, latent chain, Q/lens/kl ----
__global__ __launch_bounds__(256) void latent_kernel(
    const int* __restrict__ mask, const float* __restrict__ enc_part,
    const float* __restrict__ eps,
    const float* __restrict__ Wm, const float* __restrict__ bm,
    const float* __restrict__ Wv, const float* __restrict__ bv,
    const float* __restrict__ Wlin, const float* __restrict__ blin,
    const float* __restrict__ Wout, const float* __restrict__ bout,
    int* __restrict__ lens, float* __restrict__ Q,
    float* __restrict__ kl_acc) {
    __shared__ float s_enc[D_];
    __shared__ float s_mean[L_], s_lv[L_], s_z[L_], s_mem[D_];
    __shared__ float s_red[256];
    __shared__ int s_cnt;
    const int b = blockIdx.x;
    const int tid = threadIdx.x;
    if (tid == 0) s_cnt = 0;
    __syncthreads();
    {
        int m0 = mask[b * S_ + tid] != 0;
        int m1 = mask[b * S_ + 256 + tid] != 0;
        unsigned long long b0 = __ballot(m0), b1 = __ballot(m1);
        if ((tid & 63) == 0) atomicAdd(&s_cnt, __popcll(b0) + __popcll(b1));
    }
    __syncthreads();
    const int cnt = s_cnt;
    float e = 0.f;
#pragma unroll
    for (int o = 0; o < 8; ++o) e += enc_part[((size_t)(b * 8 + o)) * D_ + tid];
    s_enc[tid] = e / fmaxf((float)cnt, 1.f);
    __syncthreads();
    {
        const int l = tid & (L_ - 1);
        const float* W = (tid < L_) ? Wm : Wv;
        const float* bb = (tid < L_) ? bm : bv;
        float dot = bb[l];
        for (int d = 0; d < D_; ++d) dot = fmaf(s_enc[d], W[d * L_ + l], dot);
        if (tid < L_) s_mean[l] = dot; else s_lv[l] = dot;
    }
    __syncthreads();
    float klp = 0.f;
    if (tid < L_) {
        float mn = s_mean[tid], lv = s_lv[tid];
        s_z[tid] = mn + eps[b * L_ + tid] * expf(0.5f * lv);
        klp = 1.f + lv - mn * mn - expf(lv);
    }
    s_red[tid] = klp;
    __syncthreads();
    for (int s = 128; s > 0; s >>= 1) {
        if (tid < s) s_red[tid] += s_red[tid + s];
        __syncthreads();
    }
    if (tid == 0) {
        atomicAdd(kl_acc, s_red[0]);
        lens[b] = cnt;
    }
    float mem = blin[tid];
    for (int l2 = 0; l2 < L_; ++l2) mem = fmaf(s_z[l2], Wlin[l2 * D_ + tid], mem);
    s_mem[tid] = mem;
    __syncthreads();
    float qv = bout[tid];
    for (int k = 0; k < D_; ++k) qv = fmaf(s_mem[k], Wout[k * D_ + tid], qv);
    Q[b * D_ + tid] = qv;
}

// ---- scan: round-8 shape — early exit, no fence, no done counter ----
__global__ __launch_bounds__(256) void scan_kernel(
    const int* __restrict__ vocab, const unsigned short* __restrict__ embb,
    const unsigned short* __restrict__ P, const float* __restrict__ Q,
    const int* __restrict__ lens, float* __restrict__ sqp) {
    const int tid = threadIdx.x;
    const int wv = tid >> 6, lane = tid & 63;
    const int b = blockIdx.y, chunk = blockIdx.x;
    const int len = lens[b];
    const int j0 = chunk * 32 + wv * 8;
    if (j0 > len) return;  // wave-uniform

    const int c = lane * 4;
    const float4 q4 = *(const float4*)(Q + (size_t)b * D_ + c);
    int inp[8], tgt[8];
    float wgt[8];
#pragma unroll
    for (int jj = 0; jj < 8; ++jj) {
        const int j = j0 + jj;
        const bool v = (j <= len);
        const int jc = v ? j : 0;
        inp[jj] = (jc == 0) ? 1 : vocab[b * S_ + jc - 1];
        tgt[jj] = v ? ((j < len) ? vocab[b * S_ + j] : ((len < S_) ? 2 : 1)) : 1;
        wgt[jj] = v ? 1.f : 0.f;
    }
    ushort4 pv[8], tv[8];
#pragma unroll
    for (int jj = 0; jj < 8; ++jj) {
        pv[jj] = *(const ushort4*)(P + (size_t)inp[jj] * D_ + c);
        tv[jj] = *(const ushort4*)(embb + (size_t)tgt[jj] * D_ + c);
    }
    float acc = 0.f;
#pragma unroll
    for (int jj = 0; jj < 8; ++jj) {
        float d0 = bf2f(pv[jj].x) + q4.x - bf2f(tv[jj].x);
        float d1 = bf2f(pv[jj].y) + q4.y - bf2f(tv[jj].y);
        float d2 = bf2f(pv[jj].z) + q4.z - bf2f(tv[jj].z);
        float d3 = bf2f(pv[jj].w) + q4.w - bf2f(tv[jj].w);
        float s = fmaf(d0, d0, fmaf(d1, d1, fmaf(d2, d2, d3 * d3)));
        acc = fmaf(wgt[jj], s, acc);
    }
#pragma unroll
    for (int off = 32; off; off >>= 1) acc += __shfl_down(acc, off, 64);
    if (lane == 0) atomicAdd(&sqp[(b * 4 + wv + chunk) & 255], acc);
}

// ---- finalize: one block, sums sqp + lens-derived valid count ----
__global__ __launch_bounds__(256) void finalize_kernel(const float* __restrict__ ws,
                                                       float* __restrict__ out) {
    __shared__ float s_sq[256];
    __shared__ int s_vc[256];
    const int tid = threadIdx.x;
    s_sq[tid] = ws[OFF_SQP + tid];
    s_vc[tid] = ((const int*)ws)[OFF_LENS + tid] + 1;  // valid = len + 1 per b
    __syncthreads();
    for (int s = 128; s > 0; s >>= 1) {
        if (tid < s) {
            s_sq[tid] += s_sq[tid + s];
            s_vc[tid] += s_vc[tid + s];
        }
        __syncthreads();
    }
    if (tid == 0) {
        long long denom = (long long)s_vc[0] * D_;
        if (denom < 1) denom = 1;
        out[0] = s_sq[0] / (float)denom;
        out[1] = -0.5f * ws[1] / (float)B_;
    }
}

extern "C" void kernel_launch(void* const* d_in, const int* in_sizes, int n_in,
                              void* d_out, int out_size, void* d_ws, size_t ws_size,
                              hipStream_t stream) {
    const int* vocab = (const int*)d_in[0];
    const int* order = (const int*)d_in[1];
    const int* mask  = (const int*)d_in[2];
    const float* eps  = (const float*)d_in[3];
    const float* emb  = (const float*)d_in[4];
    const float* Wm   = (const float*)d_in[5];
    const float* bm   = (const float*)d_in[6];
    const float* Wv   = (const float*)d_in[7];
    const float* bv   = (const float*)d_in[8];
    const float* Wlin = (const float*)d_in[9];
    const float* blin = (const float*)d_in[10];
    const float* Wout = (const float*)d_in[11];
    const float* bout = (const float*)d_in[12];

    float* ws = (float*)d_ws;
    int* lens = (int*)(ws + OFF_LENS);
    float* Q = ws + OFF_Q;
    unsigned short* Wt = (unsigned short*)(ws + OFF_WT);
    float* enc_part = ws + OFF_EP;
    unsigned short* embb = (unsigned short*)(ws + OFF_EB);
    unsigned short* P = (unsigned short*)(ws + OFF_P);

    prep_kernel<<<2048, 256, 0, stream>>>(emb, Wout, embb, Wt, ws);
    pgemm_kernel<<<PGRID, 256, 0, stream>>>(embb, Wt, P);
    gather_kernel<<<B_ * 8, 256, 0, stream>>>(vocab, order, mask, embb, enc_part);
    latent_kernel<<<B_, 256, 0, stream>>>(mask, enc_part, eps, Wm, bm, Wv, bv,
                                          Wlin, blin, Wout, bout, lens, Q, ws + 1);
    scan_kernel<<<dim3(17, B_), 256, 0, stream>>>(vocab, embb, P, Q, lens,
                                                  ws + OFF_SQP);
    finalize_kernel<<<1, 256, 0, stream>>>(ws, (float*)d_out);
}

// Round 13
// 178.810 us; speedup vs baseline: 1.8061x; 1.1522x over previous
//
#include <hip/hip_runtime.h>

#define B_ 256
#define S_ 512
#define V_ 50000
#define D_ 256
#define L_ 128
#define PGRID 512

typedef __attribute__((ext_vector_type(8))) short short8;
typedef __attribute__((ext_vector_type(4))) float floatx4;

// ws layout (float units):
// [0..16)  ctrl: [1]=kl_acc(f32), [2]=vc(i32), [3]=done(i32)
// [16 .. +256)        sq partial slots (f32, one per b)
// [272 .. +32768)     Wt (256x256 bf16 = Wout^T)
// [33040 .. +6400000) embb (50000x256 bf16)
// [6433040 .. +6400000) P (50000x256 bf16 = emb @ Wout)
#define OFF_SQP  16
#define OFF_WT   (OFF_SQP + 256)
#define OFF_EB   (OFF_WT + 32768)
#define OFF_P    (OFF_EB + (V_ * D_ / 2))

__device__ __forceinline__ unsigned short f2bf(float x) {
    unsigned u = __float_as_uint(x);
    u += 0x7FFFu + ((u >> 16) & 1u);
    return (unsigned short)(u >> 16);
}
__device__ __forceinline__ float bf2f(unsigned short u) {
    return __uint_as_float(((unsigned)u) << 16);
}

// ---- prep: embb = bf16(emb) streaming; Wt = bf16(Wout^T); zero ctrl ----
__global__ __launch_bounds__(256) void prep_kernel(const float* __restrict__ emb,
                                                   const float* __restrict__ Wout,
                                                   unsigned short* __restrict__ embb,
                                                   unsigned short* __restrict__ Wt,
                                                   float* __restrict__ ws) {
    __shared__ float sT[64][65];
    const int tid = threadIdx.x;
    if (blockIdx.x == 0) {
        if (tid < 16) ((int*)ws)[tid] = 0;   // kl_acc, vc, done
        ws[OFF_SQP + tid] = 0.f;
    }
    if (blockIdx.x < 16) {  // Wout transpose tile (64x64)
        const int bx = blockIdx.x;
        const int k0 = (bx & 3) * 64, n0 = (bx >> 2) * 64;
        const int c = tid & 63, rg = tid >> 6;
#pragma unroll
        for (int i = 0; i < 16; ++i) {
            int r = rg * 16 + i;
            sT[c][r] = Wout[(k0 + r) * D_ + n0 + c];
        }
        __syncthreads();
#pragma unroll
        for (int i = 0; i < 16; ++i) {
            int r = rg * 16 + i;
            Wt[(size_t)(n0 + r) * D_ + k0 + c] = f2bf(sT[r][c]);
        }
    }
    const int N4 = V_ * D_ / 4;
    for (int i = blockIdx.x * 256 + tid; i < N4; i += gridDim.x * 256) {
        float4 v = ((const float4*)emb)[i];
        ushort4 h;
        h.x = f2bf(v.x); h.y = f2bf(v.y); h.z = f2bf(v.z); h.w = f2bf(v.w);
        ((ushort4*)embb)[i] = h;
    }
}

// ---- P = embb @ Wout: B-in-registers persistent GEMM, A prefetch ----
__global__ __launch_bounds__(256, 2) void pgemm_kernel(
    const unsigned short* __restrict__ embb, const unsigned short* __restrict__ Wt,
    unsigned short* __restrict__ P) {
    const int tid = threadIdx.x;
    const int wv = tid >> 6, lane = tid & 63;
    const int lo = lane & 15, hi = lane >> 4;
    const int NCH = V_ / 16;  // 3125

    short8 bfr[4][8];
    const unsigned short* wbase = Wt + (size_t)(wv * 64 + lo) * D_ + hi * 8;
#pragma unroll
    for (int nt = 0; nt < 4; ++nt)
#pragma unroll
        for (int kk = 0; kk < 8; ++kk)
            bfr[nt][kk] = *(const short8*)(wbase + nt * 16 * D_ + kk * 32);

    int ch = blockIdx.x;
    const unsigned short* abase = embb + (size_t)(ch * 16 + lo) * D_ + hi * 8;
    short8 acur[8];
#pragma unroll
    for (int kk = 0; kk < 8; ++kk) acur[kk] = *(const short8*)(abase + kk * 32);

    for (; ch < NCH; ch += PGRID) {
        const int chn = (ch + PGRID < NCH) ? (ch + PGRID) : ch;
        const unsigned short* anext = embb + (size_t)(chn * 16 + lo) * D_ + hi * 8;
        short8 anxt[8];
#pragma unroll
        for (int kk = 0; kk < 8; ++kk) anxt[kk] = *(const short8*)(anext + kk * 32);

        floatx4 acc[4];
#pragma unroll
        for (int nt = 0; nt < 4; ++nt) acc[nt] = (floatx4){0.f, 0.f, 0.f, 0.f};
#pragma unroll
        for (int kk = 0; kk < 8; ++kk)
#pragma unroll
            for (int nt = 0; nt < 4; ++nt)
                acc[nt] = __builtin_amdgcn_mfma_f32_16x16x32_bf16(
                    acur[kk], bfr[nt][kk], acc[nt], 0, 0, 0);

#pragma unroll
        for (int r = 0; r < 4; ++r) {
            unsigned short* prow = P + (size_t)(ch * 16 + hi * 4 + r) * D_ + wv * 64 + lo;
#pragma unroll
            for (int nt = 0; nt < 4; ++nt) prow[nt * 16] = f2bf(acc[nt][r]);
        }
#pragma unroll
        for (int kk = 0; kk < 8; ++kk) acur[kk] = anxt[kk];
    }
}

// ---- mega-kernel: enc + latent (Q in LDS) + scan(own b) + last-block finalize ----
__global__ __launch_bounds__(1024) void enclat_kernel(
    const int* __restrict__ vocab, const int* __restrict__ order,
    const int* __restrict__ mask, const unsigned short* __restrict__ embb,
    const unsigned short* __restrict__ P, const float* __restrict__ eps,
    const float* __restrict__ Wm, const float* __restrict__ bm,
    const float* __restrict__ Wv, const float* __restrict__ bv,
    const float* __restrict__ Wlin, const float* __restrict__ blin,
    const float* __restrict__ Wout, const float* __restrict__ bout,
    float* __restrict__ ws, float* __restrict__ out) {
    __shared__ int s_id1[S_], s_id2[S_];
    __shared__ float4 s_part[15 * 64];
    __shared__ float s_enc[D_];
    __shared__ float s_mean[L_], s_lv[L_], s_z[L_], s_mem[D_], s_Q[D_];
    __shared__ float s_red[256];
    __shared__ float s_wred[16];
    __shared__ int s_cnt, s_prev;
    const int b = blockIdx.x;
    const int tid = threadIdx.x;
    float* kl_acc = ws + 1;
    int* vc_acc = (int*)ws + 2;
    int* done = (int*)ws + 3;
    float* sqp = ws + OFF_SQP;

    if (tid == 0) s_cnt = 0;
    __syncthreads();
    // ---- phase 1: ids + cnt ----
    if (tid < S_) {
        int j = tid;
        int mk = mask[b * S_ + j];
        int id1 = 0, id2 = 0;
        if (mk) {
            id1 = vocab[b * S_ + j];
            if (j == 0) {
                id2 = 1;  // BOS at position 0
            } else {
                int oi = order[(size_t)(b * S_ + j) * 6];
                if (oi == -1) oi = 1;
                id2 = mask[b * S_ + oi] ? vocab[b * S_ + oi] : 0;  // parent from vt
            }
        }
        s_id1[j] = id1;
        s_id2[j] = id2;
        unsigned long long bal = __ballot(mk != 0);
        if ((tid & 63) == 0) atomicAdd(&s_cnt, __popcll(bal));
    }
    __syncthreads();
    const int cnt = s_cnt;  // prefix mask: valid j = [0, cnt)
    // ---- phase 2: gather mean of embb[id1]+embb[id2], deep unroll ----
    const int jg = tid >> 6, d4 = tid & 63;
    const ushort4* eb4 = (const ushort4*)embb;
    float4 a = {0.f, 0.f, 0.f, 0.f};
#pragma unroll 8
    for (int j = jg; j < cnt; j += 16) {
        ushort4 x = eb4[(size_t)s_id1[j] * 64 + d4];
        ushort4 y = eb4[(size_t)s_id2[j] * 64 + d4];
        a.x += bf2f(x.x) + bf2f(y.x);
        a.y += bf2f(x.y) + bf2f(y.y);
        a.z += bf2f(x.z) + bf2f(y.z);
        a.w += bf2f(x.w) + bf2f(y.w);
    }
    if (jg) s_part[(jg - 1) * 64 + d4] = a;
    __syncthreads();
    if (jg == 0) {
#pragma unroll
        for (int g = 0; g < 15; ++g) {
            float4 p = s_part[g * 64 + d4];
            a.x += p.x; a.y += p.y; a.z += p.z; a.w += p.w;
        }
        float inv = 1.f / fmaxf((float)cnt, 1.f);
        a.x *= inv; a.y *= inv; a.z *= inv; a.w *= inv;
        ((float4*)s_enc)[d4] = a;
    }
    __syncthreads();
    // ---- phase 3: latent (threads < 256), Q kept in LDS ----
    float dot = 0.f;
    if (tid < 256) {
        const int l = tid & (L_ - 1);
        const float* W = (tid < L_) ? Wm : Wv;
        const float* bb = (tid < L_) ? bm : bv;
        dot = bb[l];
        for (int d = 0; d < D_; ++d) dot = fmaf(s_enc[d], W[d * L_ + l], dot);
        if (tid < L_) s_mean[l] = dot; else s_lv[l] = dot;
    }
    __syncthreads();
    float klp = 0.f;
    if (tid < L_) {
        float mn = s_mean[tid], lv = s_lv[tid];
        s_z[tid] = mn + eps[b * L_ + tid] * expf(0.5f * lv);
        klp = 1.f + lv - mn * mn - expf(lv);
    }
    if (tid < 256) s_red[tid] = klp;
    __syncthreads();
    for (int s = 128; s > 0; s >>= 1) {
        if (tid < s) s_red[tid] += s_red[tid + s];
        __syncthreads();
    }
    const float kl_part = s_red[0];
    if (tid < 256) {
        float mem = blin[tid];
        for (int l2 = 0; l2 < L_; ++l2) mem = fmaf(s_z[l2], Wlin[l2 * D_ + tid], mem);
        s_mem[tid] = mem;
    }
    __syncthreads();
    if (tid < 256) {
        float qv = bout[tid];
        for (int k = 0; k < D_; ++k) qv = fmaf(s_mem[k], Wout[k * D_ + tid], qv);
        s_Q[tid] = qv;
    }
    __syncthreads();
    // ---- phase 4: scan own b, groups of 4 positions/wave, batched loads ----
    const int lane = tid & 63;
    const int c = lane * 4;
    const float4 q4 = *(const float4*)(s_Q + c);
    float acc = 0.f;
    for (int j0 = jg * 4; j0 <= cnt; j0 += 64) {
        int inp[4], tgt[4];
        float wgt[4];
#pragma unroll
        for (int u = 0; u < 4; ++u) {
            const int j = j0 + u;
            const bool v = (j <= cnt);
            const int jc = v ? j : 0;
            inp[u] = (jc == 0) ? 1 : s_id1[jc - 1];
            tgt[u] = v ? ((j < cnt) ? s_id1[j] : ((cnt < S_) ? 2 : 1)) : 1;
            wgt[u] = v ? 1.f : 0.f;
        }
        ushort4 pv[4], tv[4];
#pragma unroll
        for (int u = 0; u < 4; ++u) {
            pv[u] = *(const ushort4*)(P + (size_t)inp[u] * D_ + c);
            tv[u] = *(const ushort4*)(embb + (size_t)tgt[u] * D_ + c);
        }
#pragma unroll
        for (int u = 0; u < 4; ++u) {
            float d0 = bf2f(pv[u].x) + q4.x - bf2f(tv[u].x);
            float d1 = bf2f(pv[u].y) + q4.y - bf2f(tv[u].y);
            float d2 = bf2f(pv[u].z) + q4.z - bf2f(tv[u].z);
            float d3 = bf2f(pv[u].w) + q4.w - bf2f(tv[u].w);
            float s = fmaf(d0, d0, fmaf(d1, d1, fmaf(d2, d2, d3 * d3)));
            acc = fmaf(wgt[u], s, acc);
        }
    }
#pragma unroll
    for (int off = 32; off; off >>= 1) acc += __shfl_down(acc, off, 64);
    if (lane == 0) s_wred[jg] = acc;
    __syncthreads();
    // ---- phase 5: per-block global accumulation, last block finalizes ----
    if (tid == 0) {
        float tot = 0.f;
#pragma unroll
        for (int g = 0; g < 16; ++g) tot += s_wred[g];
        sqp[b] = tot;                 // exclusive slot
        atomicAdd(kl_acc, kl_part);
        atomicAdd(vc_acc, cnt + 1);
        __threadfence();              // make all the above device-visible
        s_prev = atomicAdd(done, 1);
    }
    __syncthreads();
    if (s_prev == B_ - 1) {
        float v = (tid < 256) ? atomicAdd(&sqp[tid], 0.f) : 0.f;  // coherent read
        if (tid < 256) s_red[tid] = v;
        __syncthreads();
        for (int s = 128; s > 0; s >>= 1) {
            if (tid < s) s_red[tid] += s_red[tid + s];
            __syncthreads();
        }
        if (tid == 0) {
            float kl = atomicAdd(kl_acc, 0.f);
            int vc = atomicAdd(vc_acc, 0);
            long long denom = (long long)vc * D_;
            if (denom < 1) denom = 1;
            out[0] = s_red[0] / (float)denom;
            out[1] = -0.5f * kl / (float)B_;
        }
    }
}

extern "C" void kernel_launch(void* const* d_in, const int* in_sizes, int n_in,
                              void* d_out, int out_size, void* d_ws, size_t ws_size,
                              hipStream_t stream) {
    const int* vocab = (const int*)d_in[0];
    const int* order = (const int*)d_in[1];
    const int* mask  = (const int*)d_in[2];
    const float* eps  = (const float*)d_in[3];
    const float* emb  = (const float*)d_in[4];
    const float* Wm   = (const float*)d_in[5];
    const float* bm   = (const float*)d_in[6];
    const float* Wv   = (const float*)d_in[7];
    const float* bv   = (const float*)d_in[8];
    const float* Wlin = (const float*)d_in[9];
    const float* blin = (const float*)d_in[10];
    const float* Wout = (const float*)d_in[11];
    const float* bout = (const float*)d_in[12];

    float* ws = (float*)d_ws;
    unsigned short* Wt = (unsigned short*)(ws + OFF_WT);
    unsigned short* embb = (unsigned short*)(ws + OFF_EB);
    unsigned short* P = (unsigned short*)(ws + OFF_P);

    prep_kernel<<<2048, 256, 0, stream>>>(emb, Wout, embb, Wt, ws);
    pgemm_kernel<<<PGRID, 256, 0, stream>>>(embb, Wt, P);
    enclat_kernel<<<B_, 1024, 0, stream>>>(vocab, order, mask, embb, P, eps,
                                           Wm, bm, Wv, bv, Wlin, blin, Wout, bout,
                                           ws, (float*)d_out);
}